// Round 2
// baseline (224.078 us; speedup 1.0000x reference)
//
#include <hip/hip_runtime.h>

// BioNorm: out = w * x^p / (sigma^p + depthwise_conv5x5(x^p, edge-pad)) + b
// B=32, C=64, H=W=112, K=5, fp32. Memory-bound floor ~160-206 MB HBM.
//
// R2: LDS-bank-conflict fix. R1 read 8-float segments at lane stride 16 B ->
// 8-way bank aliasing (2.76e7 conflict cycles = ~50% of runtime). Now each
// thread computes a 28-wide row strip: lane = (lr=tid/4, q=tid&3), LDS row
// stride ST=114 floats (114 mod 32 = 18, gcd(18,32)=2 -> lr=0..15 covers all
// 16 even bank-pair residues exactly once -> float2 row loads are exactly at
// the 128 B/clk LDS floor, zero conflicts). Halo amortized over 28 outputs:
// 23 B LDS/output vs 44 before, 3.4 LDS insts/output vs 5.
//
// Edge semantics: replicate-pad == clamped window CENTER (cw=clamp(w,2,109),
// cr=clamp(r,2,109)); taps always read real rows/cols. Per-q static index
// remap for the 2 edge columns keeps all acc[] indices compile-time constant.

#define Cch 64
#define Hh 112
#define Ww 112
#define TH 16          // output rows per block (112 = 7*16)
#define LROWS (TH + 4) // 20 staged rows
#define ST 114         // LDS row stride in floats (even, 18 mod 32)

__global__ __launch_bounds__(64) void bionorm_kernel(
    const float* __restrict__ x, const float* __restrict__ sigma,
    const float* __restrict__ pow_p, const float* __restrict__ sum_kernel,
    const float* __restrict__ weight, const float* __restrict__ bias,
    float* __restrict__ out)
{
    __shared__ float lds[LROWS * ST];

    const int rt  = blockIdx.x;   // row tile 0..6
    const int c   = blockIdx.y;
    const int b   = blockIdx.z;
    const int tid = threadIdx.x;  // 0..63, one wave
    const int r0  = rt * TH;

    // per-channel params (block-uniform -> scalar regs)
    const float p  = pow_p[c];
    const float sg = sigma[c];
    const float wc = weight[c];
    const float bc = bias[c];
    const bool  p2 = (p == 2.0f);
    const float sp = p2 ? sg * sg : __powf(sg, p);

    float kw[25];
    const float* kp = sum_kernel + c * 25;
    #pragma unroll
    for (int j = 0; j < 25; ++j) kw[j] = kp[j];

    const float* xplane = x + ((size_t)(b * Cch + c)) * Hh * Ww;

    // ---- stage x^p: 20 rows x 112 cols (28 float4 per row) ----
    for (int i = tid; i < LROWS * 28; i += 64) {
        int s = i / 28, q4 = i - s * 28;
        int g = r0 - 2 + s;
        g = g < 0 ? 0 : (g > 111 ? 111 : g);
        const float4 v = *(const float4*)(xplane + g * Ww + q4 * 4);
        float4 xp;
        if (p2) {
            xp.x = v.x * v.x; xp.y = v.y * v.y;
            xp.z = v.z * v.z; xp.w = v.w * v.w;
        } else {
            xp.x = __powf(v.x, p); xp.y = __powf(v.y, p);
            xp.z = __powf(v.z, p); xp.w = __powf(v.w, p);
        }
        *(float4*)(&lds[s * ST + q4 * 4]) = xp;
    }
    __syncthreads();

    // ---- compute: lane (lr, q) -> row r0+lr, columns [28q, 28q+28) ----
    const int lr = tid >> 2;
    const int q  = tid & 3;
    const int r  = r0 + lr;
    const int cr = r < 2 ? 2 : (r > 109 ? 109 : r);
    const int crBase = cr - r0;           // LDS row for dy=0 is crBase+0... wait: s = (cr-r0)+dy
    // taps for sum center c0 = base_t+2+j are rv[j+dx]
    int base_t = 28 * q - 2;
    base_t = base_t < 0 ? 0 : (base_t > 80 ? 80 : base_t);   // 0,26,54,80 (even)

    float acc[28];
    #pragma unroll
    for (int j = 0; j < 28; ++j) acc[j] = 0.f;

    #pragma unroll
    for (int dy = 0; dy < 5; ++dy) {
        const float* rowp = &lds[(crBase + dy) * ST + base_t];
        float rv[32];
        #pragma unroll
        for (int t = 0; t < 16; ++t) {
            const float2 v = *(const float2*)(rowp + 2 * t);
            rv[2 * t] = v.x; rv[2 * t + 1] = v.y;
        }
        #pragma unroll
        for (int dx = 0; dx < 5; ++dx) {
            const float kv = kw[dy * 5 + dx];
            #pragma unroll
            for (int j = 0; j < 28; ++j)
                acc[j] = fmaf(kv, rv[j + dx], acc[j]);
        }
    }

    // map sums to outputs: den for output col w uses center clamp(w,2,109);
    // j = clamp(w)-2-base_t. Static per (q,i) via branch on q (no dyn index).
    float sden[28];
    if (q == 0) {            // base_t=0: j = max(i-2,0)
        #pragma unroll
        for (int i = 0; i < 28; ++i) sden[i] = acc[i < 2 ? 0 : i - 2];
    } else if (q == 3) {     // base_t=80: j = min(i+2,27)
        #pragma unroll
        for (int i = 0; i < 28; ++i) sden[i] = acc[i > 25 ? 27 : i + 2];
    } else {                 // interior: j = i
        #pragma unroll
        for (int i = 0; i < 28; ++i) sden[i] = acc[i];
    }

    // numerator x^p at actual (r, w): LDS row lr+2, cols 28q.. (even-aligned)
    const float* nump = &lds[(lr + 2) * ST + 28 * q];
    float res[28];
    #pragma unroll
    for (int i = 0; i < 28; i += 2) {
        const float2 nv = *(const float2*)(nump + i);
        res[i]     = fmaf(wc * nv.x, __builtin_amdgcn_rcpf(sp + sden[i]),     bc);
        res[i + 1] = fmaf(wc * nv.y, __builtin_amdgcn_rcpf(sp + sden[i + 1]), bc);
    }

    float* orow = out + ((size_t)(b * Cch + c)) * Hh * Ww + r * Ww + 28 * q;
    #pragma unroll
    for (int u = 0; u < 7; ++u) {
        float4 o = {res[4 * u], res[4 * u + 1], res[4 * u + 2], res[4 * u + 3]};
        *(float4*)(orow + 4 * u) = o;
    }
}

extern "C" void kernel_launch(void* const* d_in, const int* in_sizes, int n_in,
                              void* d_out, int out_size, void* d_ws, size_t ws_size,
                              hipStream_t stream) {
    const float* x          = (const float*)d_in[0];
    const float* sigma      = (const float*)d_in[1];
    const float* pow_p      = (const float*)d_in[2];
    const float* sum_kernel = (const float*)d_in[3];
    const float* weight     = (const float*)d_in[4];
    const float* bias       = (const float*)d_in[5];
    float* out = (float*)d_out;

    dim3 grid(7, Cch, 32);   // (row tiles, C, B)
    dim3 block(64);
    bionorm_kernel<<<grid, block, 0, stream>>>(x, sigma, pow_p, sum_kernel,
                                               weight, bias, out);
}